// Round 6
// baseline (240.008 us; speedup 1.0000x reference)
//
#include <hip/hip_runtime.h>
#include <hip/hip_bf16.h>
#include <stdint.h>

#define N_EMBD 1024
#define N_HEAD 16
#define HEAD_DIM 64
#define T_SEQ 2048
#define BATCH 2
#define M_TOK (BATCH * T_SEQ)  // 4096

typedef short bf16x8 __attribute__((ext_vector_type(8)));
typedef float f32x4 __attribute__((ext_vector_type(4)));

__device__ __forceinline__ void gload_lds16(const void* g, void* l) {
  __builtin_amdgcn_global_load_lds(
      (const __attribute__((address_space(1))) void*)g,
      (__attribute__((address_space(3))) void*)l, 16, 0, 0);
}

__device__ __forceinline__ uint16_t f2bf(float x) {
  uint32_t u = __float_as_uint(x);
  uint32_t r = (u + 0x7FFFu + ((u >> 16) & 1u)) >> 16;
  return (uint16_t)r;
}

// ---------------- elementwise f32 -> bf16 ----------------
__global__ void convert_f32_bf16(const float* __restrict__ in,
                                 uint16_t* __restrict__ out, int n) {
  int i = (blockIdx.x * blockDim.x + threadIdx.x) * 4;
  int stride = gridDim.x * blockDim.x * 4;
  for (; i + 3 < n; i += stride) {
    float4 v = *(const float4*)(in + i);
    ushort4 o;
    o.x = f2bf(v.x); o.y = f2bf(v.y); o.z = f2bf(v.z); o.w = f2bf(v.w);
    *(ushort4*)(out + i) = o;
  }
}

// ---------------- transpose + convert: W [R][C] f32 -> Wt [C][R] bf16 ------
__global__ void transpose_convert(const float* __restrict__ W,
                                  uint16_t* __restrict__ Wt, int R, int C_) {
  __shared__ uint16_t t[64][65];
  int c0 = blockIdx.x * 64, r0 = blockIdx.y * 64;
  int lc = threadIdx.x & 63, lr4 = threadIdx.x >> 6;
#pragma unroll
  for (int rr = 0; rr < 16; ++rr) {
    int r = rr * 4 + lr4;
    t[r][lc] = f2bf(W[(size_t)(r0 + r) * C_ + c0 + lc]);
  }
  __syncthreads();
#pragma unroll
  for (int rr = 0; rr < 16; ++rr) {
    int r = rr * 4 + lr4;  // output row within tile (= source column)
    Wt[(size_t)(c0 + r) * R + r0 + lc] = t[lc][r];
  }
}

// ---------------- V slice of qkv -> Vt [BH][64][T] ----------------
__global__ void transpose_v(const uint16_t* __restrict__ qkv,
                            uint16_t* __restrict__ Vt) {
  __shared__ uint16_t t[64][65];
  int t0 = blockIdx.x * 64;
  int bh = blockIdx.y;
  int b = bh >> 4, h = bh & 15;
  int lc = threadIdx.x & 63, lr4 = threadIdx.x >> 6;
  const uint16_t* src =
      qkv + (size_t)(b * T_SEQ) * (3 * N_EMBD) + 2 * N_EMBD + h * 64;
#pragma unroll
  for (int rr = 0; rr < 16; ++rr) {
    int r = rr * 4 + lr4;  // t index within tile
    t[r][lc] = src[(size_t)(t0 + r) * (3 * N_EMBD) + lc];
  }
  __syncthreads();
  uint16_t* dst = Vt + (size_t)bh * 64 * T_SEQ;
#pragma unroll
  for (int rr = 0; rr < 16; ++rr) {
    int d = rr * 4 + lr4;
    dst[(size_t)d * T_SEQ + t0 + lc] = t[lc][d];
  }
}

// ---------------- GEMM: C[M][N] = A[M][K] * Bt[N][K]^T + bias ----------------
template <int OUT_BF16>
__global__ __launch_bounds__(256) void gemm_bt(
    const uint16_t* __restrict__ A, const uint16_t* __restrict__ Bt,
    const float* __restrict__ bias, void* __restrict__ Cv, int M, int N,
    int K) {
  __shared__ __attribute__((aligned(16))) uint16_t sA[128 * 32];
  __shared__ __attribute__((aligned(16))) uint16_t sB[128 * 32];
  int tid = threadIdx.x;
  int w = tid >> 6, l = tid & 63;
  int wm = w >> 1, wn = w & 1;
  int ql = l & 15, hi = l >> 4;
  size_t m0 = (size_t)blockIdx.x * 128, n0 = (size_t)blockIdx.y * 128;
  f32x4 acc[4][4] = {};

  for (int kt = 0; kt < K; kt += 32) {
#pragma unroll
    for (int r = 0; r < 2; ++r) {
      int base = r * 256 + (w << 6);  // wave-uniform 16B-unit index
      int idx = base + l;
      gload_lds16(A + (m0 + (idx >> 2)) * K + kt + (idx & 3) * 8, sA + base * 8);
      gload_lds16(Bt + (n0 + (idx >> 2)) * K + kt + (idx & 3) * 8, sB + base * 8);
    }
    __syncthreads();
    bf16x8 af[4], bfr[4];
#pragma unroll
    for (int i = 0; i < 4; i++)
      af[i] = *(const bf16x8*)(sA + (wm * 64 + i * 16 + ql) * 32 + hi * 8);
#pragma unroll
    for (int j = 0; j < 4; j++)
      bfr[j] = *(const bf16x8*)(sB + (wn * 64 + j * 16 + ql) * 32 + hi * 8);
#pragma unroll
    for (int i = 0; i < 4; i++)
#pragma unroll
      for (int j = 0; j < 4; j++)
        acc[i][j] = __builtin_amdgcn_mfma_f32_16x16x32_bf16(af[i], bfr[j],
                                                            acc[i][j], 0, 0, 0);
    __syncthreads();
  }

#pragma unroll
  for (int i = 0; i < 4; i++) {
    size_t m = m0 + wm * 64 + i * 16 + hi * 4;
#pragma unroll
    for (int j = 0; j < 4; j++) {
      size_t n = n0 + wn * 64 + j * 16 + ql;
      float bv = bias[n];
#pragma unroll
      for (int r = 0; r < 4; r++) {
        float v = acc[i][j][r] + bv;
        if (OUT_BF16)
          ((uint16_t*)Cv)[(m + r) * N + n] = f2bf(v);
        else
          ((float*)Cv)[(m + r) * N + n] = v;
      }
    }
  }
}

// ---------------- causal flash attention (v6) ------------------------------
// One 16-row strip per wave; 1024 blocks (4/CU, 16 waves/CU). Blocks group
// 4 equal-length strips (class c -> strips 4c+w, c+1 iters). Longest classes
// launch first (LPT). XCD-local bh (4 per XCD). Branch-free main loop;
// causal mask only in the peeled final iteration; unconditional rescale.
__global__ __launch_bounds__(256, 4) void attn_kernel(
    const uint16_t* __restrict__ qkv, const uint16_t* __restrict__ Vt,
    uint16_t* __restrict__ y) {
  int tid = threadIdx.x;
  int w = tid >> 6, l = tid & 63;
  int ql = l & 15, hi = l >> 4;
  int id = blockIdx.x;            // 0..1023
  int xcd = id & 7;
  int slot = id >> 3;             // 0..127
  int bh = xcd * 4 + (slot & 3);  // 4 bh per XCD -> K/V L2-resident
  int cls = 31 - (slot >> 2);     // long strips first (LPT)
  int s = cls * 4 + w;            // this wave's strip, 0..127
  int q0 = s * 16;
  const int n = cls + 1;          // kv-tile iterations for this strip
  int b = bh >> 4, h = bh & 15;
  const size_t rs = 3 * N_EMBD;
  const uint16_t* Qb = qkv + (size_t)(b * T_SEQ) * rs + h * 64;
  const uint16_t* Kb = Qb + N_EMBD;
  const uint16_t* Vb = Vt + (size_t)bh * 64 * T_SEQ;
  const bool lo = hi < 2;
  const int sl0 = ql + ((hi & 1) << 5);
  const int sl1 = sl0 + 16;
  const int qg = q0 + ql;

  // Q fragments, scale 1/8 folded into bf16 exponent (exact)
  bf16x8 qf0 = *(const bf16x8*)(Qb + (size_t)qg * rs + hi * 8);
  bf16x8 qf1 = *(const bf16x8*)(Qb + (size_t)qg * rs + 32 + hi * 8);
#pragma unroll
  for (int j = 0; j < 8; ++j) {
    uint16_t u = (uint16_t)qf0[j];
    qf0[j] = (short)(((u & 0x7f80u) >= 0x180u) ? (u - 0x180u) : (u & 0x8000u));
    uint16_t v = (uint16_t)qf1[j];
    qf1[j] = (short)(((v & 0x7f80u) >= 0x180u) ? (v - 0x180u) : (v & 0x8000u));
  }

  f32x4 acc[4] = {};
  float m_run = -1e30f, l_part = 0.f;
  const uint16_t* kptr = Kb + (size_t)ql * rs + hi * 8;
  const uint16_t* vptr = Vb + (size_t)ql * T_SEQ + hi * 8;

  bf16x8 kr[8];
#pragma unroll
  for (int f = 0; f < 4; ++f) {
    kr[2 * f] = *(const bf16x8*)(kptr + (size_t)(16 * f) * rs);
    kr[2 * f + 1] = *(const bf16x8*)(kptr + (size_t)(16 * f) * rs + 32);
  }

  // ---- main loop: branch-free, no mask ----
  for (int it = 0; it < n - 1; ++it) {
    const int kv0 = it << 6;
    bf16x8 vf[8];
#pragma unroll
    for (int d = 0; d < 4; ++d) {
      vf[2 * d] = *(const bf16x8*)(vptr + (size_t)(16 * d) * T_SEQ + kv0);
      vf[2 * d + 1] =
          *(const bf16x8*)(vptr + (size_t)(16 * d) * T_SEQ + kv0 + 32);
    }
    f32x4 sfr[4] = {};
    __builtin_amdgcn_s_setprio(1);
#pragma unroll
    for (int f = 0; f < 4; ++f) {
      sfr[f] =
          __builtin_amdgcn_mfma_f32_16x16x32_bf16(kr[2 * f], qf0, sfr[f], 0, 0, 0);
      sfr[f] = __builtin_amdgcn_mfma_f32_16x16x32_bf16(kr[2 * f + 1], qf1,
                                                       sfr[f], 0, 0, 0);
    }
    __builtin_amdgcn_s_setprio(0);
    // prefetch next K tile (consumed next iter or by the peel)
    {
      const uint16_t* knext = kptr + (size_t)(kv0 + 64) * rs;
#pragma unroll
      for (int f = 0; f < 4; ++f) {
        kr[2 * f] = *(const bf16x8*)(knext + (size_t)(16 * f) * rs);
        kr[2 * f + 1] = *(const bf16x8*)(knext + (size_t)(16 * f) * rs + 32);
      }
    }
    // softmax: unconditional rescale
    float sv[16];
#pragma unroll
    for (int f = 0; f < 4; ++f)
#pragma unroll
      for (int r = 0; r < 4; ++r) sv[4 * f + r] = sfr[f][r];
    float x0 = fmaxf(fmaxf(sv[0], sv[1]), fmaxf(sv[2], sv[3]));
    float x1 = fmaxf(fmaxf(sv[4], sv[5]), fmaxf(sv[6], sv[7]));
    float x2 = fmaxf(fmaxf(sv[8], sv[9]), fmaxf(sv[10], sv[11]));
    float x3 = fmaxf(fmaxf(sv[12], sv[13]), fmaxf(sv[14], sv[15]));
    float tmax = fmaxf(fmaxf(x0, x1), fmaxf(x2, x3));
    tmax = fmaxf(tmax, __shfl_xor(tmax, 16));
    tmax = fmaxf(tmax, __shfl_xor(tmax, 32));
    float m_new = fmaxf(m_run, tmax);
    float corr = __expf(m_run - m_new);
    m_run = m_new;
    l_part *= corr;
#pragma unroll
    for (int d = 0; d < 4; ++d) acc[d] *= corr;
    float pv[16];
#pragma unroll
    for (int i2 = 0; i2 < 16; ++i2) pv[i2] = __expf(sv[i2] - m_run);
    float s01 = (pv[0] + pv[1]) + (pv[2] + pv[3]);
    float s23 = (pv[4] + pv[5]) + (pv[6] + pv[7]);
    float s45 = (pv[8] + pv[9]) + (pv[10] + pv[11]);
    float s67 = (pv[12] + pv[13]) + (pv[14] + pv[15]);
    l_part += (s01 + s23) + (s45 + s67);
    uint32_t wp[8];
#pragma unroll
    for (int f = 0; f < 4; ++f) {
      asm("v_cvt_pk_bf16_f32 %0, %1, %2"
          : "=v"(wp[2 * f]) : "v"(pv[4 * f]), "v"(pv[4 * f + 1]));
      asm("v_cvt_pk_bf16_f32 %0, %1, %2"
          : "=v"(wp[2 * f + 1]) : "v"(pv[4 * f + 2]), "v"(pv[4 * f + 3]));
    }
    union { uint32_t u[4]; bf16x8 v; } pf0, pf1;
    {
      uint32_t a0 = __shfl((int)wp[0], sl0), b0 = __shfl((int)wp[2], sl0);
      uint32_t a1 = __shfl((int)wp[1], sl0), b1 = __shfl((int)wp[3], sl0);
      uint32_t a2 = __shfl((int)wp[0], sl1), b2 = __shfl((int)wp[2], sl1);
      uint32_t a3 = __shfl((int)wp[1], sl1), b3 = __shfl((int)wp[3], sl1);
      pf0.u[0] = lo ? a0 : b0; pf0.u[1] = lo ? a1 : b1;
      pf0.u[2] = lo ? a2 : b2; pf0.u[3] = lo ? a3 : b3;
    }
    {
      uint32_t a0 = __shfl((int)wp[4], sl0), b0 = __shfl((int)wp[6], sl0);
      uint32_t a1 = __shfl((int)wp[5], sl0), b1 = __shfl((int)wp[7], sl0);
      uint32_t a2 = __shfl((int)wp[4], sl1), b2 = __shfl((int)wp[6], sl1);
      uint32_t a3 = __shfl((int)wp[5], sl1), b3 = __shfl((int)wp[7], sl1);
      pf1.u[0] = lo ? a0 : b0; pf1.u[1] = lo ? a1 : b1;
      pf1.u[2] = lo ? a2 : b2; pf1.u[3] = lo ? a3 : b3;
    }
    __builtin_amdgcn_s_setprio(1);
#pragma unroll
    for (int d = 0; d < 4; ++d)
      acc[d] =
          __builtin_amdgcn_mfma_f32_16x16x32_bf16(vf[2 * d], pf0.v, acc[d], 0, 0, 0);
#pragma unroll
    for (int d = 0; d < 4; ++d)
      acc[d] = __builtin_amdgcn_mfma_f32_16x16x32_bf16(vf[2 * d + 1], pf1.v,
                                                       acc[d], 0, 0, 0);
    __builtin_amdgcn_s_setprio(0);
  }

  // ---- peeled final iteration: causal mask ----
  {
    const int kv0 = (n - 1) << 6;
    bf16x8 vf[8];
#pragma unroll
    for (int d = 0; d < 4; ++d) {
      vf[2 * d] = *(const bf16x8*)(vptr + (size_t)(16 * d) * T_SEQ + kv0);
      vf[2 * d + 1] =
          *(const bf16x8*)(vptr + (size_t)(16 * d) * T_SEQ + kv0 + 32);
    }
    f32x4 sfr[4] = {};
    __builtin_amdgcn_s_setprio(1);
#pragma unroll
    for (int f = 0; f < 4; ++f) {
      sfr[f] =
          __builtin_amdgcn_mfma_f32_16x16x32_bf16(kr[2 * f], qf0, sfr[f], 0, 0, 0);
      sfr[f] = __builtin_amdgcn_mfma_f32_16x16x32_bf16(kr[2 * f + 1], qf1,
                                                       sfr[f], 0, 0, 0);
    }
    __builtin_amdgcn_s_setprio(0);
    float sv[16];
    const int kb = kv0 + 4 * hi;
#pragma unroll
    for (int f = 0; f < 4; ++f)
#pragma unroll
      for (int r = 0; r < 4; ++r)
        sv[4 * f + r] = (kb + 16 * f + r <= qg) ? sfr[f][r] : -1e30f;
    float x0 = fmaxf(fmaxf(sv[0], sv[1]), fmaxf(sv[2], sv[3]));
    float x1 = fmaxf(fmaxf(sv[4], sv[5]), fmaxf(sv[6], sv[7]));
    float x2 = fmaxf(fmaxf(sv[8], sv[9]), fmaxf(sv[10], sv[11]));
    float x3 = fmaxf(fmaxf(sv[12], sv[13]), fmaxf(sv[14], sv[15]));
    float tmax = fmaxf(fmaxf(x0, x1), fmaxf(x2, x3));
    tmax = fmaxf(tmax, __shfl_xor(tmax, 16));
    tmax = fmaxf(tmax, __shfl_xor(tmax, 32));
    float m_new = fmaxf(m_run, tmax);
    float corr = __expf(m_run - m_new);
    m_run = m_new;
    l_part *= corr;
#pragma unroll
    for (int d = 0; d < 4; ++d) acc[d] *= corr;
    float pv[16];
#pragma unroll
    for (int i2 = 0; i2 < 16; ++i2) pv[i2] = __expf(sv[i2] - m_run);
    float s01 = (pv[0] + pv[1]) + (pv[2] + pv[3]);
    float s23 = (pv[4] + pv[5]) + (pv[6] + pv[7]);
    float s45 = (pv[8] + pv[9]) + (pv[10] + pv[11]);
    float s67 = (pv[12] + pv[13]) + (pv[14] + pv[15]);
    l_part += (s01 + s23) + (s45 + s67);
    uint32_t wp[8];
#pragma unroll
    for (int f = 0; f < 4; ++f) {
      asm("v_cvt_pk_bf16_f32 %0, %1, %2"
          : "=v"(wp[2 * f]) : "v"(pv[4 * f]), "v"(pv[4 * f + 1]));
      asm("v_cvt_pk_bf16_f32 %0, %1, %2"
          : "=v"(wp[2 * f + 1]) : "v"(pv[4 * f + 2]), "v"(pv[4 * f + 3]));
    }
    union { uint32_t u[4]; bf16x8 v; } pf0, pf1;
    {
      uint32_t a0 = __shfl((int)wp[0], sl0), b0 = __shfl((int)wp[2], sl0);
      uint32_t a1 = __shfl((int)wp[1], sl0), b1 = __shfl((int)wp[3], sl0);
      uint32_t a2 = __shfl((int)wp[0], sl1), b2 = __shfl((int)wp[2], sl1);
      uint32_t a3 = __shfl((int)wp[1], sl1), b3 = __shfl((int)wp[3], sl1);
      pf0.u[0] = lo ? a0 : b0; pf0.u[1] = lo ? a1 : b1;
      pf0.u[2] = lo ? a2 : b2; pf0.u[3] = lo ? a3 : b3;
    }
    {
      uint32_t a0 = __shfl((int)wp[4], sl0), b0 = __shfl((int)wp[6], sl0);
      uint32_t a1 = __shfl((int)wp[5], sl0), b1 = __shfl((int)wp[7], sl0);
      uint32_t a2 = __shfl((int)wp[4], sl1), b2 = __shfl((int)wp[6], sl1);
      uint32_t a3 = __shfl((int)wp[5], sl1), b3 = __shfl((int)wp[7], sl1);
      pf1.u[0] = lo ? a0 : b0; pf1.u[1] = lo ? a1 : b1;
      pf1.u[2] = lo ? a2 : b2; pf1.u[3] = lo ? a3 : b3;
    }
    __builtin_amdgcn_s_setprio(1);
#pragma unroll
    for (int d = 0; d < 4; ++d)
      acc[d] =
          __builtin_amdgcn_mfma_f32_16x16x32_bf16(vf[2 * d], pf0.v, acc[d], 0, 0, 0);
#pragma unroll
    for (int d = 0; d < 4; ++d)
      acc[d] = __builtin_amdgcn_mfma_f32_16x16x32_bf16(vf[2 * d + 1], pf1.v,
                                                       acc[d], 0, 0, 0);
    __builtin_amdgcn_s_setprio(0);
  }

  // ---- epilogue ----
  float lt = l_part + __shfl_xor(l_part, 16);
  lt += __shfl_xor(lt, 32);
  float inv = 1.0f / lt;
  uint16_t* yrow = y + (size_t)(b * T_SEQ + qg) * N_EMBD + h * 64;
#pragma unroll
  for (int d = 0; d < 4; ++d) {
    uint32_t o01, o23;
    float v0 = acc[d][0] * inv, v1 = acc[d][1] * inv;
    float v2 = acc[d][2] * inv, v3 = acc[d][3] * inv;
    asm("v_cvt_pk_bf16_f32 %0, %1, %2" : "=v"(o01) : "v"(v0), "v"(v1));
    asm("v_cvt_pk_bf16_f32 %0, %1, %2" : "=v"(o23) : "v"(v2), "v"(v3));
    *(uint32_t*)(yrow + d * 16 + hi * 4) = o01;
    *(uint32_t*)(yrow + d * 16 + hi * 4 + 2) = o23;
  }
}

extern "C" void kernel_launch(void* const* d_in, const int* in_sizes, int n_in,
                              void* d_out, int out_size, void* d_ws,
                              size_t ws_size, hipStream_t stream) {
  const float* x = (const float*)d_in[0];
  const float* Wqkv = (const float*)d_in[1];
  const float* bqkv = (const float*)d_in[2];
  const float* Wproj = (const float*)d_in[3];
  const float* bproj = (const float*)d_in[4];
  float* out = (float*)d_out;

  uint8_t* ws = (uint8_t*)d_ws;
  uint16_t* xb = (uint16_t*)(ws);                       //  8 MB: x bf16 [4096][1024]
  uint16_t* wqkvT = (uint16_t*)(ws + (8u << 20));       //  6 MB: Wqkv^T [3072][1024]
  uint16_t* wprojT = (uint16_t*)(ws + (14u << 20));     //  2 MB: Wproj^T [1024][1024]
  uint16_t* qkv = (uint16_t*)(ws + (16u << 20));        // 24 MB: qkv [4096][3072]
  uint16_t* vt = (uint16_t*)(ws + (40u << 20));         //  8 MB: V^T [32][64][2048]
  uint16_t* yb = (uint16_t*)(ws + (48u << 20));         //  8 MB: y [4096][1024]

  convert_f32_bf16<<<dim3(4096), dim3(256), 0, stream>>>(x, xb,
                                                         M_TOK * N_EMBD);
  transpose_convert<<<dim3(3072 / 64, 1024 / 64), dim3(256), 0, stream>>>(
      Wqkv, wqkvT, 1024, 3072);
  transpose_convert<<<dim3(1024 / 64, 1024 / 64), dim3(256), 0, stream>>>(
      Wproj, wprojT, 1024, 1024);
  gemm_bt<1><<<dim3(M_TOK / 128, 3072 / 128), dim3(256), 0, stream>>>(
      xb, wqkvT, bqkv, qkv, M_TOK, 3072, 1024);
  transpose_v<<<dim3(T_SEQ / 64, 32), dim3(256), 0, stream>>>(qkv, vt);
  attn_kernel<<<dim3(1024), dim3(256), 0, stream>>>(qkv, vt, yb);
  gemm_bt<0><<<dim3(M_TOK / 128, 1024 / 128), dim3(256), 0, stream>>>(
      yb, wprojT, bproj, out, M_TOK, 1024, 1024);
}

// Round 7
// 143.545 us; speedup vs baseline: 1.6720x; 1.6720x over previous
//
#include <hip/hip_runtime.h>
#include <hip/hip_bf16.h>
#include <stdint.h>

#define N_EMBD 1024
#define N_HEAD 16
#define HEAD_DIM 64
#define T_SEQ 2048
#define BATCH 2
#define M_TOK (BATCH * T_SEQ)  // 4096

typedef short bf16x8 __attribute__((ext_vector_type(8)));
typedef float f32x4 __attribute__((ext_vector_type(4)));

__device__ __forceinline__ void gload_lds16(const void* g, void* l) {
  __builtin_amdgcn_global_load_lds(
      (const __attribute__((address_space(1))) void*)g,
      (__attribute__((address_space(3))) void*)l, 16, 0, 0);
}

__device__ __forceinline__ uint16_t f2bf(float x) {
  uint32_t u = __float_as_uint(x);
  uint32_t r = (u + 0x7FFFu + ((u >> 16) & 1u)) >> 16;
  return (uint16_t)r;
}

// ---------------- elementwise f32 -> bf16 ----------------
__global__ void convert_f32_bf16(const float* __restrict__ in,
                                 uint16_t* __restrict__ out, int n) {
  int i = (blockIdx.x * blockDim.x + threadIdx.x) * 4;
  int stride = gridDim.x * blockDim.x * 4;
  for (; i + 3 < n; i += stride) {
    float4 v = *(const float4*)(in + i);
    ushort4 o;
    o.x = f2bf(v.x); o.y = f2bf(v.y); o.z = f2bf(v.z); o.w = f2bf(v.w);
    *(ushort4*)(out + i) = o;
  }
}

// ---------------- transpose + convert: W [R][C] f32 -> Wt [C][R] bf16 ------
__global__ void transpose_convert(const float* __restrict__ W,
                                  uint16_t* __restrict__ Wt, int R, int C_) {
  __shared__ uint16_t t[64][65];
  int c0 = blockIdx.x * 64, r0 = blockIdx.y * 64;
  int lc = threadIdx.x & 63, lr4 = threadIdx.x >> 6;
#pragma unroll
  for (int rr = 0; rr < 16; ++rr) {
    int r = rr * 4 + lr4;
    t[r][lc] = f2bf(W[(size_t)(r0 + r) * C_ + c0 + lc]);
  }
  __syncthreads();
#pragma unroll
  for (int rr = 0; rr < 16; ++rr) {
    int r = rr * 4 + lr4;  // output row within tile (= source column)
    Wt[(size_t)(c0 + r) * R + r0 + lc] = t[lc][r];
  }
}

// ---------------- V slice of qkv -> Vt [BH][64][T] ----------------
__global__ void transpose_v(const uint16_t* __restrict__ qkv,
                            uint16_t* __restrict__ Vt) {
  __shared__ uint16_t t[64][65];
  int t0 = blockIdx.x * 64;
  int bh = blockIdx.y;
  int b = bh >> 4, h = bh & 15;
  int lc = threadIdx.x & 63, lr4 = threadIdx.x >> 6;
  const uint16_t* src =
      qkv + (size_t)(b * T_SEQ) * (3 * N_EMBD) + 2 * N_EMBD + h * 64;
#pragma unroll
  for (int rr = 0; rr < 16; ++rr) {
    int r = rr * 4 + lr4;  // t index within tile
    t[r][lc] = src[(size_t)(t0 + r) * (3 * N_EMBD) + lc];
  }
  __syncthreads();
  uint16_t* dst = Vt + (size_t)bh * 64 * T_SEQ;
#pragma unroll
  for (int rr = 0; rr < 16; ++rr) {
    int d = rr * 4 + lr4;
    dst[(size_t)d * T_SEQ + t0 + lc] = t[lc][d];
  }
}

// ---------------- GEMM: C[M][N] = A[M][K] * Bt[N][K]^T + bias ----------------
template <int OUT_BF16>
__global__ __launch_bounds__(256) void gemm_bt(
    const uint16_t* __restrict__ A, const uint16_t* __restrict__ Bt,
    const float* __restrict__ bias, void* __restrict__ Cv, int M, int N,
    int K) {
  __shared__ __attribute__((aligned(16))) uint16_t sA[128 * 32];
  __shared__ __attribute__((aligned(16))) uint16_t sB[128 * 32];
  int tid = threadIdx.x;
  int w = tid >> 6, l = tid & 63;
  int wm = w >> 1, wn = w & 1;
  int ql = l & 15, hi = l >> 4;
  size_t m0 = (size_t)blockIdx.x * 128, n0 = (size_t)blockIdx.y * 128;
  f32x4 acc[4][4] = {};

  for (int kt = 0; kt < K; kt += 32) {
#pragma unroll
    for (int r = 0; r < 2; ++r) {
      int base = r * 256 + (w << 6);  // wave-uniform 16B-unit index
      int idx = base + l;
      gload_lds16(A + (m0 + (idx >> 2)) * K + kt + (idx & 3) * 8, sA + base * 8);
      gload_lds16(Bt + (n0 + (idx >> 2)) * K + kt + (idx & 3) * 8, sB + base * 8);
    }
    __syncthreads();
    bf16x8 af[4], bfr[4];
#pragma unroll
    for (int i = 0; i < 4; i++)
      af[i] = *(const bf16x8*)(sA + (wm * 64 + i * 16 + ql) * 32 + hi * 8);
#pragma unroll
    for (int j = 0; j < 4; j++)
      bfr[j] = *(const bf16x8*)(sB + (wn * 64 + j * 16 + ql) * 32 + hi * 8);
#pragma unroll
    for (int i = 0; i < 4; i++)
#pragma unroll
      for (int j = 0; j < 4; j++)
        acc[i][j] = __builtin_amdgcn_mfma_f32_16x16x32_bf16(af[i], bfr[j],
                                                            acc[i][j], 0, 0, 0);
    __syncthreads();
  }

#pragma unroll
  for (int i = 0; i < 4; i++) {
    size_t m = m0 + wm * 64 + i * 16 + hi * 4;
#pragma unroll
    for (int j = 0; j < 4; j++) {
      size_t n = n0 + wn * 64 + j * 16 + ql;
      float bv = bias[n];
#pragma unroll
      for (int r = 0; r < 4; r++) {
        float v = acc[i][j][r] + bv;
        if (OUT_BF16)
          ((uint16_t*)Cv)[(m + r) * N + n] = f2bf(v);
        else
          ((float*)Cv)[(m + r) * N + n] = v;
      }
    }
  }
}

// ---------------- causal flash attention (v7: LDS-staged K/V) --------------
// Block = 4 waves = 64 q-rows (wave w owns rows [qt*64+16w, +16)).
// Per kv-tile: block stages K[64][64] and V^T[64][64] into double-buffered
// LDS via 4 global_load_lds (width 16); XOR-swizzle (chunk c = d8 ^ (row&7))
// applied on the GLOBAL SOURCE address (LDS dest linear) and on ds_read.
// 2-phase pipeline: stage(t+1); compute(t); __syncthreads().
// Grid 1024: XCD-local bh (4 per XCD), LPT (large qt first).
__global__ __launch_bounds__(256, 4) void attn_kernel(
    const uint16_t* __restrict__ qkv, const uint16_t* __restrict__ Vt,
    uint16_t* __restrict__ y) {
  __shared__ __attribute__((aligned(16))) uint16_t sK[2][64 * 64];
  __shared__ __attribute__((aligned(16))) uint16_t sV[2][64 * 64];

  int tid = threadIdx.x;
  int w = tid >> 6, l = tid & 63;
  int ql = l & 15, hi = l >> 4;
  int id = blockIdx.x;                 // 0..1023
  int xcd = id & 7;
  int bh = xcd * 4 + ((id >> 3) & 3);  // 4 bh per XCD -> K/V L2-resident
  int qt = 31 - (id >> 5);             // LPT: heavy q-tiles first
  int b = bh >> 4, h = bh & 15;
  const size_t rs = 3 * N_EMBD;
  const uint16_t* Qb = qkv + (size_t)(b * T_SEQ) * rs + h * 64;
  const uint16_t* Kb = Qb + N_EMBD;
  const uint16_t* Vb = Vt + (size_t)bh * 64 * T_SEQ;
  const bool lo = hi < 2;
  const int sl0 = ql + ((hi & 1) << 5);
  const int sl1 = sl0 + 16;
  const int qloc = w * 16 + ql;              // row within 64-row q-tile
  const int qg = qt * 64 + qloc;             // absolute q row

  // Q fragments, scale 1/8 folded into bf16 exponent (exact)
  bf16x8 qf0 = *(const bf16x8*)(Qb + (size_t)qg * rs + hi * 8);
  bf16x8 qf1 = *(const bf16x8*)(Qb + (size_t)qg * rs + 32 + hi * 8);
#pragma unroll
  for (int j = 0; j < 8; ++j) {
    uint16_t u = (uint16_t)qf0[j];
    qf0[j] = (short)(((u & 0x7f80u) >= 0x180u) ? (u - 0x180u) : (u & 0x8000u));
    uint16_t v = (uint16_t)qf1[j];
    qf1[j] = (short)(((v & 0x7f80u) >= 0x180u) ? (v - 0x180u) : (v & 0x8000u));
  }

  f32x4 acc[4] = {};
  float m_run = -1e30f, l_part = 0.f;
  const int xr = (ql & 7) * 8;  // read-side XOR (uint16 units)

  // ---- prologue: stage tile 0 into buffer 0 ----
  {
#pragma unroll
    for (int s2 = 0; s2 < 2; ++s2) {
      int base16 = s2 * 256 + w * 64;  // wave-uniform 16B-chunk index
      int idx = base16 + l;
      int row = idx >> 3, c = idx & 7;
      int d8 = c ^ (row & 7);          // pre-swizzled source chunk
      gload_lds16(Kb + (size_t)row * rs + d8 * 8, &sK[0][0] + base16 * 8);
      gload_lds16(Vb + (size_t)row * T_SEQ + 0 + d8 * 8,
                  &sV[0][0] + base16 * 8);
    }
  }
  __syncthreads();

  int cur = 0;
  for (int t = 0; t <= qt; ++t) {
    // ---- stage next tile into the other buffer (hidden under compute) ----
    if (t < qt) {
      const int kvn = (t + 1) << 6;
#pragma unroll
      for (int s2 = 0; s2 < 2; ++s2) {
        int base16 = s2 * 256 + w * 64;
        int idx = base16 + l;
        int row = idx >> 3, c = idx & 7;
        int d8 = c ^ (row & 7);
        gload_lds16(Kb + (size_t)(kvn + row) * rs + d8 * 8,
                    &sK[cur ^ 1][0] + base16 * 8);
        gload_lds16(Vb + (size_t)row * T_SEQ + kvn + d8 * 8,
                    &sV[cur ^ 1][0] + base16 * 8);
      }
    }
    // ---- QK^T from LDS (fragments identical across the 4 waves) ----
    const uint16_t* kb_l = &sK[cur][0];
    const uint16_t* vb_l = &sV[cur][0];
    f32x4 sfr[4] = {};
    __builtin_amdgcn_s_setprio(1);
#pragma unroll
    for (int f = 0; f < 4; ++f) {
      bf16x8 k0 = *(const bf16x8*)(kb_l + (16 * f + ql) * 64 + ((hi * 8) ^ xr));
      bf16x8 k1 =
          *(const bf16x8*)(kb_l + (16 * f + ql) * 64 + (((4 + hi) * 8) ^ xr));
      sfr[f] = __builtin_amdgcn_mfma_f32_16x16x32_bf16(k0, qf0, sfr[f], 0, 0, 0);
      sfr[f] = __builtin_amdgcn_mfma_f32_16x16x32_bf16(k1, qf1, sfr[f], 0, 0, 0);
    }
    __builtin_amdgcn_s_setprio(0);
    // ---- softmax (mask only on the diagonal tile; uniform branch) ----
    float sv[16];
    if (t == qt) {
      const int kb0 = 4 * hi;
#pragma unroll
      for (int f = 0; f < 4; ++f)
#pragma unroll
        for (int r = 0; r < 4; ++r)
          sv[4 * f + r] = (16 * f + kb0 + r <= qloc) ? sfr[f][r] : -1e30f;
    } else {
#pragma unroll
      for (int f = 0; f < 4; ++f)
#pragma unroll
        for (int r = 0; r < 4; ++r) sv[4 * f + r] = sfr[f][r];
    }
    float x0 = fmaxf(fmaxf(sv[0], sv[1]), fmaxf(sv[2], sv[3]));
    float x1 = fmaxf(fmaxf(sv[4], sv[5]), fmaxf(sv[6], sv[7]));
    float x2 = fmaxf(fmaxf(sv[8], sv[9]), fmaxf(sv[10], sv[11]));
    float x3 = fmaxf(fmaxf(sv[12], sv[13]), fmaxf(sv[14], sv[15]));
    float tmax = fmaxf(fmaxf(x0, x1), fmaxf(x2, x3));
    tmax = fmaxf(tmax, __shfl_xor(tmax, 16));
    tmax = fmaxf(tmax, __shfl_xor(tmax, 32));
    float m_new = fmaxf(m_run, tmax);
    float corr = __expf(m_run - m_new);
    m_run = m_new;
    l_part *= corr;
#pragma unroll
    for (int d = 0; d < 4; ++d) acc[d] *= corr;
    float pv[16];
#pragma unroll
    for (int i2 = 0; i2 < 16; ++i2) pv[i2] = __expf(sv[i2] - m_run);
    float s01 = (pv[0] + pv[1]) + (pv[2] + pv[3]);
    float s23 = (pv[4] + pv[5]) + (pv[6] + pv[7]);
    float s45 = (pv[8] + pv[9]) + (pv[10] + pv[11]);
    float s67 = (pv[12] + pv[13]) + (pv[14] + pv[15]);
    l_part += (s01 + s23) + (s45 + s67);
    // ---- pack P to bf16, redistribute to PV B-frag layout ----
    uint32_t wp[8];
#pragma unroll
    for (int f = 0; f < 4; ++f) {
      asm("v_cvt_pk_bf16_f32 %0, %1, %2"
          : "=v"(wp[2 * f]) : "v"(pv[4 * f]), "v"(pv[4 * f + 1]));
      asm("v_cvt_pk_bf16_f32 %0, %1, %2"
          : "=v"(wp[2 * f + 1]) : "v"(pv[4 * f + 2]), "v"(pv[4 * f + 3]));
    }
    union { uint32_t u[4]; bf16x8 v; } pf0, pf1;
    {
      uint32_t a0 = __shfl((int)wp[0], sl0), b0 = __shfl((int)wp[2], sl0);
      uint32_t a1 = __shfl((int)wp[1], sl0), b1 = __shfl((int)wp[3], sl0);
      uint32_t a2 = __shfl((int)wp[0], sl1), b2 = __shfl((int)wp[2], sl1);
      uint32_t a3 = __shfl((int)wp[1], sl1), b3 = __shfl((int)wp[3], sl1);
      pf0.u[0] = lo ? a0 : b0; pf0.u[1] = lo ? a1 : b1;
      pf0.u[2] = lo ? a2 : b2; pf0.u[3] = lo ? a3 : b3;
    }
    {
      uint32_t a0 = __shfl((int)wp[4], sl0), b0 = __shfl((int)wp[6], sl0);
      uint32_t a1 = __shfl((int)wp[5], sl0), b1 = __shfl((int)wp[7], sl0);
      uint32_t a2 = __shfl((int)wp[4], sl1), b2 = __shfl((int)wp[6], sl1);
      uint32_t a3 = __shfl((int)wp[5], sl1), b3 = __shfl((int)wp[7], sl1);
      pf1.u[0] = lo ? a0 : b0; pf1.u[1] = lo ? a1 : b1;
      pf1.u[2] = lo ? a2 : b2; pf1.u[3] = lo ? a3 : b3;
    }
    // ---- PV from LDS V^T tile ----
    __builtin_amdgcn_s_setprio(1);
#pragma unroll
    for (int d = 0; d < 4; ++d) {
      bf16x8 v0 = *(const bf16x8*)(vb_l + (16 * d + ql) * 64 + ((hi * 8) ^ xr));
      acc[d] = __builtin_amdgcn_mfma_f32_16x16x32_bf16(v0, pf0.v, acc[d], 0, 0, 0);
    }
#pragma unroll
    for (int d = 0; d < 4; ++d) {
      bf16x8 v1 =
          *(const bf16x8*)(vb_l + (16 * d + ql) * 64 + (((4 + hi) * 8) ^ xr));
      acc[d] = __builtin_amdgcn_mfma_f32_16x16x32_bf16(v1, pf1.v, acc[d], 0, 0, 0);
    }
    __builtin_amdgcn_s_setprio(0);
    __syncthreads();  // stage(t+1) drained; all waves done reading buf[cur]
    cur ^= 1;
  }

  // ---- epilogue ----
  float lt = l_part + __shfl_xor(l_part, 16);
  lt += __shfl_xor(lt, 32);
  float inv = 1.0f / lt;
  uint16_t* yrow = y + (size_t)(b * T_SEQ + qg) * N_EMBD + h * 64;
#pragma unroll
  for (int d = 0; d < 4; ++d) {
    uint32_t o01, o23;
    float v0 = acc[d][0] * inv, v1 = acc[d][1] * inv;
    float v2 = acc[d][2] * inv, v3 = acc[d][3] * inv;
    asm("v_cvt_pk_bf16_f32 %0, %1, %2" : "=v"(o01) : "v"(v0), "v"(v1));
    asm("v_cvt_pk_bf16_f32 %0, %1, %2" : "=v"(o23) : "v"(v2), "v"(v3));
    *(uint32_t*)(yrow + d * 16 + hi * 4) = o01;
    *(uint32_t*)(yrow + d * 16 + hi * 4 + 2) = o23;
  }
}

extern "C" void kernel_launch(void* const* d_in, const int* in_sizes, int n_in,
                              void* d_out, int out_size, void* d_ws,
                              size_t ws_size, hipStream_t stream) {
  const float* x = (const float*)d_in[0];
  const float* Wqkv = (const float*)d_in[1];
  const float* bqkv = (const float*)d_in[2];
  const float* Wproj = (const float*)d_in[3];
  const float* bproj = (const float*)d_in[4];
  float* out = (float*)d_out;

  uint8_t* ws = (uint8_t*)d_ws;
  uint16_t* xb = (uint16_t*)(ws);                       //  8 MB: x bf16 [4096][1024]
  uint16_t* wqkvT = (uint16_t*)(ws + (8u << 20));       //  6 MB: Wqkv^T [3072][1024]
  uint16_t* wprojT = (uint16_t*)(ws + (14u << 20));     //  2 MB: Wproj^T [1024][1024]
  uint16_t* qkv = (uint16_t*)(ws + (16u << 20));        // 24 MB: qkv [4096][3072]
  uint16_t* vt = (uint16_t*)(ws + (40u << 20));         //  8 MB: V^T [32][64][2048]
  uint16_t* yb = (uint16_t*)(ws + (48u << 20));         //  8 MB: y [4096][1024]

  convert_f32_bf16<<<dim3(4096), dim3(256), 0, stream>>>(x, xb,
                                                         M_TOK * N_EMBD);
  transpose_convert<<<dim3(3072 / 64, 1024 / 64), dim3(256), 0, stream>>>(
      Wqkv, wqkvT, 1024, 3072);
  transpose_convert<<<dim3(1024 / 64, 1024 / 64), dim3(256), 0, stream>>>(
      Wproj, wprojT, 1024, 1024);
  gemm_bt<1><<<dim3(M_TOK / 128, 3072 / 128), dim3(256), 0, stream>>>(
      xb, wqkvT, bqkv, qkv, M_TOK, 3072, 1024);
  transpose_v<<<dim3(T_SEQ / 64, 32), dim3(256), 0, stream>>>(qkv, vt);
  attn_kernel<<<dim3(1024), dim3(256), 0, stream>>>(qkv, vt, yb);
  gemm_bt<0><<<dim3(M_TOK / 128, 1024 / 128), dim3(256), 0, stream>>>(
      yb, wprojT, bproj, out, M_TOK, 1024, 1024);
}

// Round 8
// 125.272 us; speedup vs baseline: 1.9159x; 1.1459x over previous
//
#include <hip/hip_runtime.h>
#include <hip/hip_bf16.h>
#include <stdint.h>

#define N_EMBD 1024
#define N_HEAD 16
#define HEAD_DIM 64
#define T_SEQ 2048
#define BATCH 2
#define M_TOK (BATCH * T_SEQ)  // 4096

typedef short bf16x8 __attribute__((ext_vector_type(8)));
typedef float f32x4 __attribute__((ext_vector_type(4)));

__device__ __forceinline__ void gload_lds16(const void* g, void* l) {
  __builtin_amdgcn_global_load_lds(
      (const __attribute__((address_space(1))) void*)g,
      (__attribute__((address_space(3))) void*)l, 16, 0, 0);
}

__device__ __forceinline__ uint16_t f2bf(float x) {
  uint32_t u = __float_as_uint(x);
  uint32_t r = (u + 0x7FFFu + ((u >> 16) & 1u)) >> 16;
  return (uint16_t)r;
}

// ---------------- elementwise f32 -> bf16 ----------------
__global__ void convert_f32_bf16(const float* __restrict__ in,
                                 uint16_t* __restrict__ out, int n) {
  int i = (blockIdx.x * blockDim.x + threadIdx.x) * 4;
  int stride = gridDim.x * blockDim.x * 4;
  for (; i + 3 < n; i += stride) {
    float4 v = *(const float4*)(in + i);
    ushort4 o;
    o.x = f2bf(v.x); o.y = f2bf(v.y); o.z = f2bf(v.z); o.w = f2bf(v.w);
    *(ushort4*)(out + i) = o;
  }
}

// ---------------- transpose + convert: W [R][C] f32 -> Wt [C][R] bf16 ------
__global__ void transpose_convert(const float* __restrict__ W,
                                  uint16_t* __restrict__ Wt, int R, int C_) {
  __shared__ uint16_t t[64][65];
  int c0 = blockIdx.x * 64, r0 = blockIdx.y * 64;
  int lc = threadIdx.x & 63, lr4 = threadIdx.x >> 6;
#pragma unroll
  for (int rr = 0; rr < 16; ++rr) {
    int r = rr * 4 + lr4;
    t[r][lc] = f2bf(W[(size_t)(r0 + r) * C_ + c0 + lc]);
  }
  __syncthreads();
#pragma unroll
  for (int rr = 0; rr < 16; ++rr) {
    int r = rr * 4 + lr4;  // output row within tile (= source column)
    Wt[(size_t)(c0 + r) * R + r0 + lc] = t[lc][r];
  }
}

// ---------------- V slice of qkv -> Vt [BH][64][T] ----------------
__global__ void transpose_v(const uint16_t* __restrict__ qkv,
                            uint16_t* __restrict__ Vt) {
  __shared__ uint16_t t[64][65];
  int t0 = blockIdx.x * 64;
  int bh = blockIdx.y;
  int b = bh >> 4, h = bh & 15;
  int lc = threadIdx.x & 63, lr4 = threadIdx.x >> 6;
  const uint16_t* src =
      qkv + (size_t)(b * T_SEQ) * (3 * N_EMBD) + 2 * N_EMBD + h * 64;
#pragma unroll
  for (int rr = 0; rr < 16; ++rr) {
    int r = rr * 4 + lr4;  // t index within tile
    t[r][lc] = src[(size_t)(t0 + r) * (3 * N_EMBD) + lc];
  }
  __syncthreads();
  uint16_t* dst = Vt + (size_t)bh * 64 * T_SEQ;
#pragma unroll
  for (int rr = 0; rr < 16; ++rr) {
    int d = rr * 4 + lr4;
    dst[(size_t)d * T_SEQ + t0 + lc] = t[lc][d];
  }
}

// ---------------- GEMM: C[M][N] = A[M][K] * Bt[N][K]^T + bias ----------------
// 128x128 tile, BK=32, 4 waves (2x2). DOUBLE-BUFFERED 2-phase K-loop:
// issue stage(t+1) BEFORE ds_read+MFMA of tile t; one barrier per K-step.
// Stage latency hides under compute (T3-minimum skeleton).
template <int OUT_BF16>
__global__ __launch_bounds__(256) void gemm_bt(
    const uint16_t* __restrict__ A, const uint16_t* __restrict__ Bt,
    const float* __restrict__ bias, void* __restrict__ Cv, int M, int N,
    int K) {
  __shared__ __attribute__((aligned(16))) uint16_t sA[2][128 * 32];
  __shared__ __attribute__((aligned(16))) uint16_t sB[2][128 * 32];
  int tid = threadIdx.x;
  int w = tid >> 6, l = tid & 63;
  int wm = w >> 1, wn = w & 1;
  int ql = l & 15, hi = l >> 4;
  size_t m0 = (size_t)blockIdx.x * 128, n0 = (size_t)blockIdx.y * 128;
  f32x4 acc[4][4] = {};

  // ---- prologue: stage tile 0 into buffer 0 ----
#pragma unroll
  for (int r = 0; r < 2; ++r) {
    int base = r * 256 + (w << 6);  // wave-uniform 16B-unit index
    int idx = base + l;
    gload_lds16(A + (m0 + (idx >> 2)) * K + (idx & 3) * 8, &sA[0][0] + base * 8);
    gload_lds16(Bt + (n0 + (idx >> 2)) * K + (idx & 3) * 8, &sB[0][0] + base * 8);
  }
  __syncthreads();

  int cur = 0;
  for (int kt = 0; kt < K; kt += 32) {
    // ---- issue next tile's staging FIRST (overlaps with compute below) ----
    if (kt + 32 < K) {
#pragma unroll
      for (int r = 0; r < 2; ++r) {
        int base = r * 256 + (w << 6);
        int idx = base + l;
        gload_lds16(A + (m0 + (idx >> 2)) * K + kt + 32 + (idx & 3) * 8,
                    &sA[cur ^ 1][0] + base * 8);
        gload_lds16(Bt + (n0 + (idx >> 2)) * K + kt + 32 + (idx & 3) * 8,
                    &sB[cur ^ 1][0] + base * 8);
      }
    }
    // ---- compute tile t from buf[cur] ----
    bf16x8 af[4], bfr[4];
#pragma unroll
    for (int i = 0; i < 4; i++)
      af[i] = *(const bf16x8*)(&sA[cur][0] + (wm * 64 + i * 16 + ql) * 32 + hi * 8);
#pragma unroll
    for (int j = 0; j < 4; j++)
      bfr[j] = *(const bf16x8*)(&sB[cur][0] + (wn * 64 + j * 16 + ql) * 32 + hi * 8);
#pragma unroll
    for (int i = 0; i < 4; i++)
#pragma unroll
      for (int j = 0; j < 4; j++)
        acc[i][j] = __builtin_amdgcn_mfma_f32_16x16x32_bf16(af[i], bfr[j],
                                                            acc[i][j], 0, 0, 0);
    // barrier drains vmcnt (next tile staged) + lgkmcnt (my reads done)
    __syncthreads();
    cur ^= 1;
  }

#pragma unroll
  for (int i = 0; i < 4; i++) {
    size_t m = m0 + wm * 64 + i * 16 + hi * 4;
#pragma unroll
    for (int j = 0; j < 4; j++) {
      size_t n = n0 + wn * 64 + j * 16 + ql;
      float bv = bias[n];
#pragma unroll
      for (int r = 0; r < 4; r++) {
        float v = acc[i][j][r] + bv;
        if (OUT_BF16)
          ((uint16_t*)Cv)[(m + r) * N + n] = f2bf(v);
        else
          ((float*)Cv)[(m + r) * N + n] = v;
      }
    }
  }
}

// ---------------- causal flash attention (v7: LDS-staged K/V) --------------
// Block = 4 waves = 64 q-rows (wave w owns rows [qt*64+16w, +16)).
// Per kv-tile: block stages K[64][64] and V^T[64][64] into double-buffered
// LDS via 4 global_load_lds (width 16); XOR-swizzle (chunk c = d8 ^ (row&7))
// applied on the GLOBAL SOURCE address (LDS dest linear) and on ds_read.
// 2-phase pipeline: stage(t+1); compute(t); __syncthreads().
// Grid 1024: XCD-local bh (4 per XCD), LPT (large qt first).
__global__ __launch_bounds__(256, 4) void attn_kernel(
    const uint16_t* __restrict__ qkv, const uint16_t* __restrict__ Vt,
    uint16_t* __restrict__ y) {
  __shared__ __attribute__((aligned(16))) uint16_t sK[2][64 * 64];
  __shared__ __attribute__((aligned(16))) uint16_t sV[2][64 * 64];

  int tid = threadIdx.x;
  int w = tid >> 6, l = tid & 63;
  int ql = l & 15, hi = l >> 4;
  int id = blockIdx.x;                 // 0..1023
  int xcd = id & 7;
  int bh = xcd * 4 + ((id >> 3) & 3);  // 4 bh per XCD -> K/V L2-resident
  int qt = 31 - (id >> 5);             // LPT: heavy q-tiles first
  int b = bh >> 4, h = bh & 15;
  const size_t rs = 3 * N_EMBD;
  const uint16_t* Qb = qkv + (size_t)(b * T_SEQ) * rs + h * 64;
  const uint16_t* Kb = Qb + N_EMBD;
  const uint16_t* Vb = Vt + (size_t)bh * 64 * T_SEQ;
  const bool lo = hi < 2;
  const int sl0 = ql + ((hi & 1) << 5);
  const int sl1 = sl0 + 16;
  const int qloc = w * 16 + ql;              // row within 64-row q-tile
  const int qg = qt * 64 + qloc;             // absolute q row

  // Q fragments, scale 1/8 folded into bf16 exponent (exact)
  bf16x8 qf0 = *(const bf16x8*)(Qb + (size_t)qg * rs + hi * 8);
  bf16x8 qf1 = *(const bf16x8*)(Qb + (size_t)qg * rs + 32 + hi * 8);
#pragma unroll
  for (int j = 0; j < 8; ++j) {
    uint16_t u = (uint16_t)qf0[j];
    qf0[j] = (short)(((u & 0x7f80u) >= 0x180u) ? (u - 0x180u) : (u & 0x8000u));
    uint16_t v = (uint16_t)qf1[j];
    qf1[j] = (short)(((v & 0x7f80u) >= 0x180u) ? (v - 0x180u) : (v & 0x8000u));
  }

  f32x4 acc[4] = {};
  float m_run = -1e30f, l_part = 0.f;
  const int xr = (ql & 7) * 8;  // read-side XOR (uint16 units)

  // ---- prologue: stage tile 0 into buffer 0 ----
  {
#pragma unroll
    for (int s2 = 0; s2 < 2; ++s2) {
      int base16 = s2 * 256 + w * 64;  // wave-uniform 16B-chunk index
      int idx = base16 + l;
      int row = idx >> 3, c = idx & 7;
      int d8 = c ^ (row & 7);          // pre-swizzled source chunk
      gload_lds16(Kb + (size_t)row * rs + d8 * 8, &sK[0][0] + base16 * 8);
      gload_lds16(Vb + (size_t)row * T_SEQ + 0 + d8 * 8,
                  &sV[0][0] + base16 * 8);
    }
  }
  __syncthreads();

  int cur = 0;
  for (int t = 0; t <= qt; ++t) {
    // ---- stage next tile into the other buffer (hidden under compute) ----
    if (t < qt) {
      const int kvn = (t + 1) << 6;
#pragma unroll
      for (int s2 = 0; s2 < 2; ++s2) {
        int base16 = s2 * 256 + w * 64;
        int idx = base16 + l;
        int row = idx >> 3, c = idx & 7;
        int d8 = c ^ (row & 7);
        gload_lds16(Kb + (size_t)(kvn + row) * rs + d8 * 8,
                    &sK[cur ^ 1][0] + base16 * 8);
        gload_lds16(Vb + (size_t)row * T_SEQ + kvn + d8 * 8,
                    &sV[cur ^ 1][0] + base16 * 8);
      }
    }
    // ---- QK^T from LDS (fragments identical across the 4 waves) ----
    const uint16_t* kb_l = &sK[cur][0];
    const uint16_t* vb_l = &sV[cur][0];
    f32x4 sfr[4] = {};
    __builtin_amdgcn_s_setprio(1);
#pragma unroll
    for (int f = 0; f < 4; ++f) {
      bf16x8 k0 = *(const bf16x8*)(kb_l + (16 * f + ql) * 64 + ((hi * 8) ^ xr));
      bf16x8 k1 =
          *(const bf16x8*)(kb_l + (16 * f + ql) * 64 + (((4 + hi) * 8) ^ xr));
      sfr[f] = __builtin_amdgcn_mfma_f32_16x16x32_bf16(k0, qf0, sfr[f], 0, 0, 0);
      sfr[f] = __builtin_amdgcn_mfma_f32_16x16x32_bf16(k1, qf1, sfr[f], 0, 0, 0);
    }
    __builtin_amdgcn_s_setprio(0);
    // ---- softmax (mask only on the diagonal tile; uniform branch) ----
    float sv[16];
    if (t == qt) {
      const int kb0 = 4 * hi;
#pragma unroll
      for (int f = 0; f < 4; ++f)
#pragma unroll
        for (int r = 0; r < 4; ++r)
          sv[4 * f + r] = (16 * f + kb0 + r <= qloc) ? sfr[f][r] : -1e30f;
    } else {
#pragma unroll
      for (int f = 0; f < 4; ++f)
#pragma unroll
        for (int r = 0; r < 4; ++r) sv[4 * f + r] = sfr[f][r];
    }
    float x0 = fmaxf(fmaxf(sv[0], sv[1]), fmaxf(sv[2], sv[3]));
    float x1 = fmaxf(fmaxf(sv[4], sv[5]), fmaxf(sv[6], sv[7]));
    float x2 = fmaxf(fmaxf(sv[8], sv[9]), fmaxf(sv[10], sv[11]));
    float x3 = fmaxf(fmaxf(sv[12], sv[13]), fmaxf(sv[14], sv[15]));
    float tmax = fmaxf(fmaxf(x0, x1), fmaxf(x2, x3));
    tmax = fmaxf(tmax, __shfl_xor(tmax, 16));
    tmax = fmaxf(tmax, __shfl_xor(tmax, 32));
    float m_new = fmaxf(m_run, tmax);
    float corr = __expf(m_run - m_new);
    m_run = m_new;
    l_part *= corr;
#pragma unroll
    for (int d = 0; d < 4; ++d) acc[d] *= corr;
    float pv[16];
#pragma unroll
    for (int i2 = 0; i2 < 16; ++i2) pv[i2] = __expf(sv[i2] - m_run);
    float s01 = (pv[0] + pv[1]) + (pv[2] + pv[3]);
    float s23 = (pv[4] + pv[5]) + (pv[6] + pv[7]);
    float s45 = (pv[8] + pv[9]) + (pv[10] + pv[11]);
    float s67 = (pv[12] + pv[13]) + (pv[14] + pv[15]);
    l_part += (s01 + s23) + (s45 + s67);
    // ---- pack P to bf16, redistribute to PV B-frag layout ----
    uint32_t wp[8];
#pragma unroll
    for (int f = 0; f < 4; ++f) {
      asm("v_cvt_pk_bf16_f32 %0, %1, %2"
          : "=v"(wp[2 * f]) : "v"(pv[4 * f]), "v"(pv[4 * f + 1]));
      asm("v_cvt_pk_bf16_f32 %0, %1, %2"
          : "=v"(wp[2 * f + 1]) : "v"(pv[4 * f + 2]), "v"(pv[4 * f + 3]));
    }
    union { uint32_t u[4]; bf16x8 v; } pf0, pf1;
    {
      uint32_t a0 = __shfl((int)wp[0], sl0), b0 = __shfl((int)wp[2], sl0);
      uint32_t a1 = __shfl((int)wp[1], sl0), b1 = __shfl((int)wp[3], sl0);
      uint32_t a2 = __shfl((int)wp[0], sl1), b2 = __shfl((int)wp[2], sl1);
      uint32_t a3 = __shfl((int)wp[1], sl1), b3 = __shfl((int)wp[3], sl1);
      pf0.u[0] = lo ? a0 : b0; pf0.u[1] = lo ? a1 : b1;
      pf0.u[2] = lo ? a2 : b2; pf0.u[3] = lo ? a3 : b3;
    }
    {
      uint32_t a0 = __shfl((int)wp[4], sl0), b0 = __shfl((int)wp[6], sl0);
      uint32_t a1 = __shfl((int)wp[5], sl0), b1 = __shfl((int)wp[7], sl0);
      uint32_t a2 = __shfl((int)wp[4], sl1), b2 = __shfl((int)wp[6], sl1);
      uint32_t a3 = __shfl((int)wp[5], sl1), b3 = __shfl((int)wp[7], sl1);
      pf1.u[0] = lo ? a0 : b0; pf1.u[1] = lo ? a1 : b1;
      pf1.u[2] = lo ? a2 : b2; pf1.u[3] = lo ? a3 : b3;
    }
    // ---- PV from LDS V^T tile ----
    __builtin_amdgcn_s_setprio(1);
#pragma unroll
    for (int d = 0; d < 4; ++d) {
      bf16x8 v0 = *(const bf16x8*)(vb_l + (16 * d + ql) * 64 + ((hi * 8) ^ xr));
      acc[d] = __builtin_amdgcn_mfma_f32_16x16x32_bf16(v0, pf0.v, acc[d], 0, 0, 0);
    }
#pragma unroll
    for (int d = 0; d < 4; ++d) {
      bf16x8 v1 =
          *(const bf16x8*)(vb_l + (16 * d + ql) * 64 + (((4 + hi) * 8) ^ xr));
      acc[d] = __builtin_amdgcn_mfma_f32_16x16x32_bf16(v1, pf1.v, acc[d], 0, 0, 0);
    }
    __builtin_amdgcn_s_setprio(0);
    __syncthreads();  // stage(t+1) drained; all waves done reading buf[cur]
    cur ^= 1;
  }

  // ---- epilogue ----
  float lt = l_part + __shfl_xor(l_part, 16);
  lt += __shfl_xor(lt, 32);
  float inv = 1.0f / lt;
  uint16_t* yrow = y + (size_t)(b * T_SEQ + qg) * N_EMBD + h * 64;
#pragma unroll
  for (int d = 0; d < 4; ++d) {
    uint32_t o01, o23;
    float v0 = acc[d][0] * inv, v1 = acc[d][1] * inv;
    float v2 = acc[d][2] * inv, v3 = acc[d][3] * inv;
    asm("v_cvt_pk_bf16_f32 %0, %1, %2" : "=v"(o01) : "v"(v0), "v"(v1));
    asm("v_cvt_pk_bf16_f32 %0, %1, %2" : "=v"(o23) : "v"(v2), "v"(v3));
    *(uint32_t*)(yrow + d * 16 + hi * 4) = o01;
    *(uint32_t*)(yrow + d * 16 + hi * 4 + 2) = o23;
  }
}

extern "C" void kernel_launch(void* const* d_in, const int* in_sizes, int n_in,
                              void* d_out, int out_size, void* d_ws,
                              size_t ws_size, hipStream_t stream) {
  const float* x = (const float*)d_in[0];
  const float* Wqkv = (const float*)d_in[1];
  const float* bqkv = (const float*)d_in[2];
  const float* Wproj = (const float*)d_in[3];
  const float* bproj = (const float*)d_in[4];
  float* out = (float*)d_out;

  uint8_t* ws = (uint8_t*)d_ws;
  uint16_t* xb = (uint16_t*)(ws);                       //  8 MB: x bf16 [4096][1024]
  uint16_t* wqkvT = (uint16_t*)(ws + (8u << 20));       //  6 MB: Wqkv^T [3072][1024]
  uint16_t* wprojT = (uint16_t*)(ws + (14u << 20));     //  2 MB: Wproj^T [1024][1024]
  uint16_t* qkv = (uint16_t*)(ws + (16u << 20));        // 24 MB: qkv [4096][3072]
  uint16_t* vt = (uint16_t*)(ws + (40u << 20));         //  8 MB: V^T [32][64][2048]
  uint16_t* yb = (uint16_t*)(ws + (48u << 20));         //  8 MB: y [4096][1024]

  convert_f32_bf16<<<dim3(4096), dim3(256), 0, stream>>>(x, xb,
                                                         M_TOK * N_EMBD);
  transpose_convert<<<dim3(3072 / 64, 1024 / 64), dim3(256), 0, stream>>>(
      Wqkv, wqkvT, 1024, 3072);
  transpose_convert<<<dim3(1024 / 64, 1024 / 64), dim3(256), 0, stream>>>(
      Wproj, wprojT, 1024, 1024);
  gemm_bt<1><<<dim3(M_TOK / 128, 3072 / 128), dim3(256), 0, stream>>>(
      xb, wqkvT, bqkv, qkv, M_TOK, 3072, 1024);
  transpose_v<<<dim3(T_SEQ / 64, 32), dim3(256), 0, stream>>>(qkv, vt);
  attn_kernel<<<dim3(1024), dim3(256), 0, stream>>>(qkv, vt, yb);
  gemm_bt<0><<<dim3(M_TOK / 128, 1024 / 128), dim3(256), 0, stream>>>(
      yb, wprojT, bproj, out, M_TOK, 1024, 1024);
}